// Round 24
// baseline (117.549 us; speedup 1.0000x reference)
//
#include <hip/hip_runtime.h>
#include <stdint.h>

#define Bn 2048
#define Dn 1024
#define Hn 2048
#define On 512
#define En 8

typedef float f32x4 __attribute__((ext_vector_type(4)));
typedef unsigned char u8;

__device__ __forceinline__ void gload16(const void* g, void* l) {
  __builtin_amdgcn_global_load_lds((const uint32_t*)g, (uint32_t*)l, 16, 0, 0);
}

__device__ __forceinline__ u8 f2fp8(float v) {
  int w = __builtin_amdgcn_cvt_pk_fp8_f32(v, v, 0, false);
  return (u8)(w & 0xff);
}

__device__ __forceinline__ uint32_t pk4_fp8(float a, float b, float c, float d) {
  int w = __builtin_amdgcn_cvt_pk_fp8_f32(a, b, 0, false);
  w = __builtin_amdgcn_cvt_pk_fp8_f32(c, d, w, true);
  return (uint32_t)w;
}

// ---------------- init: zero counts/cursors every launch (determinism) ----------------
__global__ void init_kernel(int* counts, int* cursors) {
  int t = threadIdx.x;
  if (t < En) { counts[t] = 0; cursors[t] = 0; }
}

// == fused prep: gating+x->fp8 (contiguous-16/lane) | tcast fc1_w->fp8 | tcast fc2_w->fp8 ==
#define NB_G (Bn / 8)                         // 256 blocks x 8 rows
#define NB_T1 ((Dn / 256) * (Hn / 64) * En)   // 4*32*8 = 1024
#define NB_T2 ((Hn / 256) * (On / 64) * En)   // 8*8*8  = 512
#define WSCALE 64.0f

// 256(r) x 64(c) transpose tile -> fp8 (x WSCALE). Stride-65 LDS (2-way banks both sides).
__device__ __forceinline__ void tcast_f8_256(const float* __restrict__ inp,
                                             u8* __restrict__ outp,
                                             int R, int C, int r0, int c0, uint32_t* L) {
  int t = threadIdx.x;
  int cc4 = (t & 15) * 4;   // col base 0..60
  int rg = t >> 4;          // 0..15
#pragma unroll
  for (int p = 0; p < 4; p++) {
    int rbase = p * 64 + rg * 4;
    float4 v0 = *(const float4*)&inp[(size_t)(r0 + rbase + 0) * C + c0 + cc4];
    float4 v1 = *(const float4*)&inp[(size_t)(r0 + rbase + 1) * C + c0 + cc4];
    float4 v2 = *(const float4*)&inp[(size_t)(r0 + rbase + 2) * C + c0 + cc4];
    float4 v3 = *(const float4*)&inp[(size_t)(r0 + rbase + 3) * C + c0 + cc4];
    uint32_t wds[4];
    wds[0] = pk4_fp8(v0.x * WSCALE, v1.x * WSCALE, v2.x * WSCALE, v3.x * WSCALE);
    wds[1] = pk4_fp8(v0.y * WSCALE, v1.y * WSCALE, v2.y * WSCALE, v3.y * WSCALE);
    wds[2] = pk4_fp8(v0.z * WSCALE, v1.z * WSCALE, v2.z * WSCALE, v3.z * WSCALE);
    wds[3] = pk4_fp8(v0.w * WSCALE, v1.w * WSCALE, v2.w * WSCALE, v3.w * WSCALE);
    int rd = p * 16 + rg;
#pragma unroll
    for (int j = 0; j < 4; j++) L[(cc4 + j) * 65 + rd] = wds[j];
  }
  __syncthreads();
  int c = t >> 2, q = t & 3;  // output row c (0..63), 64B chunk q
  uint32_t dw[16];
#pragma unroll
  for (int i = 0; i < 16; i++) dw[i] = L[c * 65 + q * 16 + i];
  u8* op = &outp[(size_t)(c0 + c) * R + r0 + q * 64];
#pragma unroll
  for (int s = 0; s < 4; s++) {
    int4 o = make_int4((int)dw[4 * s], (int)dw[4 * s + 1], (int)dw[4 * s + 2],
                       (int)dw[4 * s + 3]);
    *(int4*)(op + 16 * s) = o;
  }
}

__global__ __launch_bounds__(256) void prep_kernel(
    const float* __restrict__ x, const float* __restrict__ wg,
    const float* __restrict__ fc1w, const float* __restrict__ fc2w,
    u8* __restrict__ x_f8, u8* __restrict__ w1t8, u8* __restrict__ w2t8,
    int* __restrict__ top_idx, float* __restrict__ gates, int* __restrict__ counts) {
  __shared__ __align__(16) uint32_t smem[64 * 65];  // 16.3 KB transpose tile
  __shared__ int lcnt[En];
  int bid = blockIdx.x;
  int t = threadIdx.x;

  if (bid < NB_G) {
    // ---- gating + x->fp8: 8 rows/block; lane owns 16 CONTIGUOUS d (coalesced x io) ----
    if (t < En) lcnt[t] = 0;
    __syncthreads();
    int w = t >> 6, lane = t & 63;
#pragma unroll
    for (int r = 0; r < 2; r++) {
      int b = bid * 8 + w * 2 + r;
      const float4* xr = (const float4*)(x + (size_t)b * Dn) + lane * 4;
      float acc[En];
#pragma unroll
      for (int e = 0; e < En; e++) acc[e] = 0.f;
      uint32_t xw[4];
#pragma unroll
      for (int q = 0; q < 4; q++) {
        float4 v = xr[q];
        xw[q] = pk4_fp8(v.x, v.y, v.z, v.w);
        int d0 = lane * 16 + q * 4;
        const float* wp = wg + (size_t)d0 * En;
#pragma unroll
        for (int i = 0; i < 4; i++) {
          float xv = ((const float*)&v)[i];
          float4 wa = *(const float4*)(wp + i * En);
          float4 wb = *(const float4*)(wp + i * En + 4);
          acc[0] += xv * wa.x; acc[1] += xv * wa.y;
          acc[2] += xv * wa.z; acc[3] += xv * wa.w;
          acc[4] += xv * wb.x; acc[5] += xv * wb.y;
          acc[6] += xv * wb.z; acc[7] += xv * wb.w;
        }
      }
      *(int4*)(x_f8 + (size_t)b * Dn + lane * 16) =
          make_int4((int)xw[0], (int)xw[1], (int)xw[2], (int)xw[3]);
#pragma unroll
      for (int off = 32; off; off >>= 1) {
#pragma unroll
        for (int e = 0; e < En; e++) acc[e] += __shfl_down(acc[e], off);
      }
      if (lane == 0) {
        float best = -1e30f, second = -1e30f; int bi = 0, si = 0;
#pragma unroll
        for (int e = 0; e < En; e++) {
          float l = acc[e];
          if (l > best) { second = best; si = bi; best = l; bi = e; }
          else if (l > second) { second = l; si = e; }
        }
        float e1 = expf(second - best);
        float inv = 1.f / (1.f + e1);
        top_idx[2 * b] = bi; top_idx[2 * b + 1] = si;
        gates[2 * b] = inv;  gates[2 * b + 1] = e1 * inv;
        atomicAdd(&lcnt[bi], 1);
        atomicAdd(&lcnt[si], 1);
      }
    }
    __syncthreads();
    if (t < En) {
      int c = lcnt[t];
      if (c) atomicAdd(&counts[t], c);
    }
  } else if (bid < NB_G + NB_T1) {
    // ---- fc1_w [E][Dn][Hn] -> w1t8 [E][Hn][Dn] fp8 ----
    int idx = bid - NB_G;
    constexpr int TPE = (Dn / 256) * (Hn / 64);
    int z = idx / TPE, rem = idx % TPE;
    int r0 = (rem / (Hn / 64)) * 256, c0 = (rem % (Hn / 64)) * 64;
    tcast_f8_256(fc1w + (size_t)z * Dn * Hn, w1t8 + (size_t)z * Dn * Hn, Dn, Hn, r0, c0, smem);
  } else {
    // ---- fc2_w [E][Hn][On] -> w2t8 [E][On][Hn] fp8 ----
    int idx = bid - NB_G - NB_T1;
    constexpr int TPE = (Hn / 256) * (On / 64);
    int z = idx / TPE, rem = idx % TPE;
    int r0 = (rem / (On / 64)) * 256, c0 = (rem % (On / 64)) * 64;
    tcast_f8_256(fc2w + (size_t)z * Hn * On, w2t8 + (size_t)z * Hn * On, Hn, On, r0, c0, smem);
  }
}

// -------- assign rows to compact slots (offsets computed inline from counts) --------
__global__ void assign_kernel(const int* __restrict__ top_idx, const int* __restrict__ counts,
                              int* cursors, int* __restrict__ s2r, int* __restrict__ r2s) {
  int b = blockIdx.x * 256 + threadIdx.x;
  if (b >= Bn) return;
  int offs[En];
  int s = 0;
#pragma unroll
  for (int e = 0; e < En; e++) { offs[e] = s; s += counts[e]; }
#pragma unroll
  for (int k = 0; k < 2; k++) {
    int e = top_idx[2 * b + k];
    int pos = atomicAdd(&cursors[e], 1);
    int slot = offs[e] + pos;
    s2r[slot] = b;
    r2s[2 * b + k] = slot;
  }
}

// ---- fp8 grouped GEMM: 64x64 x 64B-K-step, 4 waves (2Mx2N), mfma_f32_16x16x32_fp8_fp8 ----
// r16-r20 proven structure (112.0 us path). W pre-scaled x64 -> epilogue unscales 1/64.
template <bool FC1, int N, int K, int SPLITK>
__global__ __launch_bounds__(256, 8) void fp8_gemm_kernel(
    const u8* __restrict__ A, const u8* __restrict__ WT,
    const float* __restrict__ bias, const int* __restrict__ counts,
    const int* __restrict__ s2r,
    u8* __restrict__ outH8, float* __restrict__ outL, float* __restrict__ outLX) {
  constexpr int NBL = N / 64;
  constexpr int KS = K / SPLITK;
  constexpr int NT = KS / 64;
  int e = blockIdx.z;
  int cnt = counts[e];
  int rb = blockIdx.y;
  if (rb * 64 >= cnt) return;
  int base = 0;
#pragma unroll
  for (int i = 0; i < En; i++) base += (i < e) ? counts[i] : 0;
  int ks = blockIdx.x / NBL;
  int nb = (blockIdx.x % NBL) * 64;
  int k0 = ks * KS;
  __shared__ __align__(16) u8 As[64 * 64];  // 4 KB
  __shared__ __align__(16) u8 Bs[64 * 64];  // 4 KB
  int t = threadIdx.x;
  int lane = t & 63, w = t >> 6;
  int wr = w >> 1, wc = w & 1;

  int srow = t >> 2;                           // 0..63 staging row
  int sslot = (t & 3) ^ ((srow >> 1) & 3);     // pre-swizzled global 16B slot
  int scol = sslot * 16;

  int lr = rb * 64 + srow;
  int lrc = lr < cnt ? lr : cnt - 1;
  const u8* aptr = A + (size_t)(FC1 ? s2r[base + lrc] : (base + lrc)) * K + k0 + scol;
  const u8* bptr = WT + ((size_t)e * N + nb + srow) * K + k0 + scol;

  f32x4 zero = {0.f, 0.f, 0.f, 0.f};
  f32x4 acc[2][2];
#pragma unroll
  for (int m = 0; m < 2; m++)
#pragma unroll
    for (int n = 0; n < 2; n++) acc[m][n] = zero;

  int a_r = wr * 32 + (lane & 15);       // A fragment row
  int b_r = wc * 32 + (lane & 15);       // B fragment row
  int rkey = ((lane & 15) >> 1) & 3;     // (row>>1)&3 (row bases mult of 16 -> invariant)
  int slb = (lane >> 4) >> 1;            // logical 16B-slot sub-index (0/1)
  int half = ((lane >> 4) & 1) * 8;      // 8B half within slot

  for (int kt = 0; kt < NT; kt++) {
    gload16(aptr + kt * 64, &As[t * 16]);   // linear dest: row t>>2, slot t&3
    gload16(bptr + kt * 64, &Bs[t * 16]);
    __syncthreads();  // drains vmcnt before LDS reads
#pragma unroll
    for (int kk = 0; kk < 2; kk++) {
      long af[2], bfr[2];
#pragma unroll
      for (int m = 0; m < 2; m++)
        af[m] = *(const long*)(As + (a_r + m * 16) * 64 +
                               (((kk * 2 + slb) ^ rkey) << 4) + half);
#pragma unroll
      for (int n = 0; n < 2; n++)
        bfr[n] = *(const long*)(Bs + (b_r + n * 16) * 64 +
                                (((kk * 2 + slb) ^ rkey) << 4) + half);
#pragma unroll
      for (int m = 0; m < 2; m++)
#pragma unroll
        for (int n = 0; n < 2; n++)
          acc[m][n] = __builtin_amdgcn_mfma_f32_16x16x32_fp8_fp8(af[m], bfr[n], acc[m][n], 0, 0, 0);
    }
    __syncthreads();  // protect LDS before next stage
  }

  // epilogue: D layout col=lane&15, row=(lane>>4)*4+i; unscale 1/64
  const float INV = 1.0f / WSCALE;
  float* dst = (SPLITK > 1 && ks > 0) ? (outLX + (size_t)(ks - 1) * (2 * Bn * On)) : outL;
  int lr0 = rb * 64 + wr * 32;
#pragma unroll
  for (int m = 0; m < 2; m++) {
#pragma unroll
    for (int i = 0; i < 4; i++) {
      int orow = lr0 + m * 16 + (lane >> 4) * 4 + i;
      if (orow < cnt) {
        int slot = base + orow;
#pragma unroll
        for (int n = 0; n < 2; n++) {
          int col = nb + wc * 32 + n * 16 + (lane & 15);
          if (FC1) {
            float v = acc[m][n][i] * INV + bias[e * N + col];
            float g = 0.5f * v * (1.0f + erff(v * 0.70710678118654752f));
            outH8[(size_t)slot * N + col] = f2fp8(g);
          } else {
            float v = acc[m][n][i] * INV + (ks == 0 ? bias[e * N + col] : 0.f);
            dst[(size_t)slot * N + col] = v;
          }
        }
      }
    }
  }
}

// ---------------- combine: sum 2 split-K partials, logsoftmax over O=512, weighted sum ----------------
__device__ __forceinline__ float blk_reduce(float v, bool ismax) {
  __shared__ float sbuf[4];
  int lane = threadIdx.x & 63, w = threadIdx.x >> 6;
#pragma unroll
  for (int off = 32; off; off >>= 1) {
    float o = __shfl_down(v, off);
    v = ismax ? fmaxf(v, o) : (v + o);
  }
  __syncthreads();
  if (lane == 0) sbuf[w] = v;
  __syncthreads();
  float r = sbuf[0];
#pragma unroll
  for (int i = 1; i < 4; i++) r = ismax ? fmaxf(r, sbuf[i]) : (r + sbuf[i]);
  return r;
}

__global__ void combine_kernel(const float* __restrict__ l2a, const float* __restrict__ l2x,
                               const int* __restrict__ r2s, const float* __restrict__ gates,
                               float* __restrict__ out) {
  int b = blockIdx.x, t = threadIdx.x;
  float c0 = 0.f, c1 = 0.f;
#pragma unroll
  for (int k = 0; k < 2; k++) {
    int slot = r2s[2 * b + k];
    float g = gates[2 * b + k];
    const float* lp0 = l2a + (size_t)slot * On;
    const float* lp1 = l2x + (size_t)slot * On;
    float v0 = lp0[t] + lp1[t];
    float v1 = lp0[t + 256] + lp1[t + 256];
    float m = blk_reduce(fmaxf(v0, v1), true);
    float s = blk_reduce(expf(v0 - m) + expf(v1 - m), false);
    float lse = m + logf(s);
    c0 += g * expf(v0 - lse);
    c1 += g * expf(v1 - lse);
  }
  const float EPSv = 2.220446049250313e-16f;
  out[(size_t)b * On + t] = logf(fmaxf(c0, EPSv));
  out[(size_t)b * On + t + 256] = logf(fmaxf(c1, EPSv));
}

extern "C" void kernel_launch(void* const* d_in, const int* in_sizes, int n_in,
                              void* d_out, int out_size, void* d_ws, size_t ws_size,
                              hipStream_t stream) {
  const float* x = (const float*)d_in[0];
  const float* wgate = (const float*)d_in[1];
  const float* fc1w = (const float*)d_in[2];
  const float* fc1b = (const float*)d_in[3];
  const float* fc2w = (const float*)d_in[4];
  const float* fc2b = (const float*)d_in[5];
  float* out = (float*)d_out;

  char* ws = (char*)d_ws;
  size_t o = 0;
  u8* x_f8      = (u8*)(ws + o);    o += (size_t)Bn * Dn;              // 2 MB
  u8* w1t8      = (u8*)(ws + o);    o += (size_t)En * Hn * Dn;         // 16 MB [E][H][D] fp8
  u8* w2t8      = (u8*)(ws + o);    o += (size_t)En * On * Hn;         // 8 MB  [E][O][H] fp8
  u8* hbuf8     = (u8*)(ws + o);    o += (size_t)2 * Bn * Hn;          // 4 MB  [slot][H] fp8
  float* l2buf  = (float*)(ws + o); o += (size_t)2 * Bn * On * 4;      // 8 MB partial 0
  float* l2bufX = (float*)(ws + o); o += (size_t)2 * Bn * On * 4;      // 8 MB partial 1
  int* top_idx  = (int*)(ws + o);   o += (size_t)Bn * 2 * 4;
  float* gates  = (float*)(ws + o); o += (size_t)Bn * 2 * 4;
  int* r2s      = (int*)(ws + o);   o += (size_t)Bn * 2 * 4;
  int* s2r      = (int*)(ws + o);   o += (size_t)2 * Bn * 4;
  int* counts   = (int*)(ws + o);   o += 64;
  int* cursors  = (int*)(ws + o);   o += 64;

  hipLaunchKernelGGL(init_kernel, dim3(1), dim3(64), 0, stream, counts, cursors);
  hipLaunchKernelGGL(prep_kernel, dim3(NB_G + NB_T1 + NB_T2), dim3(256), 0, stream,
                     x, wgate, fc1w, fc2w, x_f8, w1t8, w2t8, top_idx, gates, counts);
  hipLaunchKernelGGL(assign_kernel, dim3(Bn / 256), dim3(256), 0, stream,
                     top_idx, counts, cursors, s2r, r2s);
  hipLaunchKernelGGL((fp8_gemm_kernel<true, Hn, Dn, 1>), dim3(Hn / 64, 32, En), dim3(256),
                     0, stream, x_f8, w1t8, fc1b, counts, s2r, hbuf8,
                     (float*)nullptr, (float*)nullptr);
  hipLaunchKernelGGL((fp8_gemm_kernel<false, On, Hn, 2>), dim3((On / 64) * 2, 32, En), dim3(256),
                     0, stream, hbuf8, w2t8, fc2b, counts, s2r, (u8*)nullptr,
                     l2buf, l2bufX);
  hipLaunchKernelGGL(combine_kernel, dim3(Bn), dim3(256), 0, stream, l2buf, l2bufX, r2s, gates, out);
}

// Round 25
// 115.334 us; speedup vs baseline: 1.0192x; 1.0192x over previous
//
#include <hip/hip_runtime.h>
#include <stdint.h>

#define Bn 2048
#define Dn 1024
#define Hn 2048
#define On 512
#define En 8

typedef float f32x4 __attribute__((ext_vector_type(4)));
typedef unsigned char u8;

__device__ __forceinline__ void gload16(const void* g, void* l) {
  __builtin_amdgcn_global_load_lds((const uint32_t*)g, (uint32_t*)l, 16, 0, 0);
}

__device__ __forceinline__ u8 f2fp8(float v) {
  int w = __builtin_amdgcn_cvt_pk_fp8_f32(v, v, 0, false);
  return (u8)(w & 0xff);
}

__device__ __forceinline__ uint32_t pk4_fp8(float a, float b, float c, float d) {
  int w = __builtin_amdgcn_cvt_pk_fp8_f32(a, b, 0, false);
  w = __builtin_amdgcn_cvt_pk_fp8_f32(c, d, w, true);
  return (uint32_t)w;
}

// ---------------- init: zero counts/cursors every launch (determinism) ----------------
__global__ void init_kernel(int* counts, int* cursors) {
  int t = threadIdx.x;
  if (t < En) { counts[t] = 0; cursors[t] = 0; }
}

#define WSCALE 64.0f
#define NB_G (Bn / 8)                          // 256 gating blocks
#define NB_T1 ((Dn / 256) * (Hn / 64) * En)    // 1024 w1-transpose blocks (256-row tiles)

// 256(r) x 64(c) transpose tile -> fp8 (x WSCALE). Stride-65 LDS (2-way banks both sides).
__device__ __forceinline__ void tcast_f8_256(const float* __restrict__ inp,
                                             u8* __restrict__ outp,
                                             int R, int C, int r0, int c0, uint32_t* L) {
  int t = threadIdx.x;
  int cc4 = (t & 15) * 4;
  int rg = t >> 4;
#pragma unroll
  for (int p = 0; p < 4; p++) {
    int rbase = p * 64 + rg * 4;
    float4 v0 = *(const float4*)&inp[(size_t)(r0 + rbase + 0) * C + c0 + cc4];
    float4 v1 = *(const float4*)&inp[(size_t)(r0 + rbase + 1) * C + c0 + cc4];
    float4 v2 = *(const float4*)&inp[(size_t)(r0 + rbase + 2) * C + c0 + cc4];
    float4 v3 = *(const float4*)&inp[(size_t)(r0 + rbase + 3) * C + c0 + cc4];
    uint32_t wds[4];
    wds[0] = pk4_fp8(v0.x * WSCALE, v1.x * WSCALE, v2.x * WSCALE, v3.x * WSCALE);
    wds[1] = pk4_fp8(v0.y * WSCALE, v1.y * WSCALE, v2.y * WSCALE, v3.y * WSCALE);
    wds[2] = pk4_fp8(v0.z * WSCALE, v1.z * WSCALE, v2.z * WSCALE, v3.z * WSCALE);
    wds[3] = pk4_fp8(v0.w * WSCALE, v1.w * WSCALE, v2.w * WSCALE, v3.w * WSCALE);
    int rd = p * 16 + rg;
#pragma unroll
    for (int j = 0; j < 4; j++) L[(cc4 + j) * 65 + rd] = wds[j];
  }
  __syncthreads();
  int c = t >> 2, q = t & 3;
  uint32_t dw[16];
#pragma unroll
  for (int i = 0; i < 16; i++) dw[i] = L[c * 65 + q * 16 + i];
  u8* op = &outp[(size_t)(c0 + c) * R + r0 + q * 64];
#pragma unroll
  for (int s = 0; s < 4; s++) {
    int4 o = make_int4((int)dw[4 * s], (int)dw[4 * s + 1], (int)dw[4 * s + 2],
                       (int)dw[4 * s + 3]);
    *(int4*)(op + 16 * s) = o;
  }
}

// 64(r) x 64(c) transpose tile -> fp8 (x WSCALE). Stride-17 LDS dwords, 4.4 KB.
__device__ __forceinline__ void tcast_f8_64(const float* __restrict__ inp,
                                            u8* __restrict__ outp,
                                            int R, int C, int r0, int c0, uint32_t* L) {
  int t = threadIdx.x;
  int cc4 = (t & 15) * 4;
  int rg = t >> 4;
  float4 v0 = *(const float4*)&inp[(size_t)(r0 + rg * 4 + 0) * C + c0 + cc4];
  float4 v1 = *(const float4*)&inp[(size_t)(r0 + rg * 4 + 1) * C + c0 + cc4];
  float4 v2 = *(const float4*)&inp[(size_t)(r0 + rg * 4 + 2) * C + c0 + cc4];
  float4 v3 = *(const float4*)&inp[(size_t)(r0 + rg * 4 + 3) * C + c0 + cc4];
  uint32_t wds[4];
  wds[0] = pk4_fp8(v0.x * WSCALE, v1.x * WSCALE, v2.x * WSCALE, v3.x * WSCALE);
  wds[1] = pk4_fp8(v0.y * WSCALE, v1.y * WSCALE, v2.y * WSCALE, v3.y * WSCALE);
  wds[2] = pk4_fp8(v0.z * WSCALE, v1.z * WSCALE, v2.z * WSCALE, v3.z * WSCALE);
  wds[3] = pk4_fp8(v0.w * WSCALE, v1.w * WSCALE, v2.w * WSCALE, v3.w * WSCALE);
#pragma unroll
  for (int j = 0; j < 4; j++) L[(cc4 + j) * 17 + rg] = wds[j];
  __syncthreads();
  int c = t >> 2, q = t & 3;
  int4 o;
#pragma unroll
  for (int i = 0; i < 4; i++) ((int*)&o)[i] = (int)L[c * 17 + q * 4 + i];
  *(int4*)&outp[(size_t)(c0 + c) * R + r0 + q * 16] = o;
}

// == prep: gating+x->fp8 (no-LDS strided, r20-proven) | w1 transpose ONLY ==
__global__ __launch_bounds__(256) void prep_kernel(
    const float* __restrict__ x, const float* __restrict__ wg,
    const float* __restrict__ fc1w,
    u8* __restrict__ x_f8, u8* __restrict__ w1t8,
    int* __restrict__ top_idx, float* __restrict__ gates, int* __restrict__ counts) {
  __shared__ __align__(16) uint32_t smem[64 * 65];  // 16.3 KB transpose tile
  __shared__ int lcnt[En];
  int bid = blockIdx.x;
  int t = threadIdx.x;

  if (bid < NB_G) {
    if (t < En) lcnt[t] = 0;
    __syncthreads();
    int w = t >> 6, lane = t & 63;
#pragma unroll
    for (int r = 0; r < 2; r++) {
      int b = bid * 8 + w * 2 + r;
      const float* xr = x + (size_t)b * Dn;
      u8* xo = x_f8 + (size_t)b * Dn;
      float acc[En];
#pragma unroll
      for (int e = 0; e < En; e++) acc[e] = 0.f;
#pragma unroll
      for (int j = 0; j < 16; j++) {
        int d = lane + j * 64;
        float xv = xr[d];
        xo[d] = f2fp8(xv);
        float4 wa = *(const float4*)(wg + (size_t)d * En);
        float4 wb = *(const float4*)(wg + (size_t)d * En + 4);
        acc[0] += xv * wa.x; acc[1] += xv * wa.y;
        acc[2] += xv * wa.z; acc[3] += xv * wa.w;
        acc[4] += xv * wb.x; acc[5] += xv * wb.y;
        acc[6] += xv * wb.z; acc[7] += xv * wb.w;
      }
#pragma unroll
      for (int off = 32; off; off >>= 1) {
#pragma unroll
        for (int e = 0; e < En; e++) acc[e] += __shfl_down(acc[e], off);
      }
      if (lane == 0) {
        float best = -1e30f, second = -1e30f; int bi = 0, si = 0;
#pragma unroll
        for (int e = 0; e < En; e++) {
          float l = acc[e];
          if (l > best) { second = best; si = bi; best = l; bi = e; }
          else if (l > second) { second = l; si = e; }
        }
        float e1 = expf(second - best);
        float inv = 1.f / (1.f + e1);
        top_idx[2 * b] = bi; top_idx[2 * b + 1] = si;
        gates[2 * b] = inv;  gates[2 * b + 1] = e1 * inv;
        atomicAdd(&lcnt[bi], 1);
        atomicAdd(&lcnt[si], 1);
      }
    }
    __syncthreads();
    if (t < En) {
      int c = lcnt[t];
      if (c) atomicAdd(&counts[t], c);
    }
  } else {
    // ---- fc1_w [E][Dn][Hn] -> w1t8 [E][Hn][Dn] fp8 (256-row tiles) ----
    int idx = bid - NB_G;
    constexpr int TPE = (Dn / 256) * (Hn / 64);
    int z = idx / TPE, rem = idx % TPE;
    int r0 = (rem / (Hn / 64)) * 256, c0 = (rem % (Hn / 64)) * 64;
    tcast_f8_256(fc1w + (size_t)z * Dn * Hn, w1t8 + (size_t)z * Dn * Hn, Dn, Hn, r0, c0, smem);
  }
}

// -------- assign rows to compact slots (offsets computed inline from counts) --------
__global__ void assign_kernel(const int* __restrict__ top_idx, const int* __restrict__ counts,
                              int* cursors, int* __restrict__ s2r, int* __restrict__ r2s) {
  int b = blockIdx.x * 256 + threadIdx.x;
  if (b >= Bn) return;
  int offs[En];
  int s = 0;
#pragma unroll
  for (int e = 0; e < En; e++) { offs[e] = s; s += counts[e]; }
#pragma unroll
  for (int k = 0; k < 2; k++) {
    int e = top_idx[2 * b + k];
    int pos = atomicAdd(&cursors[e], 1);
    int slot = offs[e] + pos;
    s2r[slot] = b;
    r2s[2 * b + k] = slot;
  }
}

// ==== FUSED fc1 GEMM + w2-weight transpose (range-decoded 1D grid) ====
// GEMM blocks: bid < 8192 -> 64x64 fp8 GEMM (r16-r20 proven structure, early-exit).
// Transpose blocks: bid >= 8192 -> fc2_w [E][Hn][On] -> w2t8 [E][On][Hn] (64x64 tiles).
// The fc1 GEMM is latency-bound with idle memory pipes; the 32 MB w2 read rides in the
// slack instead of serializing in prep. LDS unioned at 8 KB (transpose needs 4.4 KB).
__global__ __launch_bounds__(256, 8) void fc1_fused_kernel(
    const u8* __restrict__ A, const u8* __restrict__ WT,
    const float* __restrict__ bias, const int* __restrict__ counts,
    const int* __restrict__ s2r, u8* __restrict__ outH8,
    const float* __restrict__ fc2w, u8* __restrict__ w2t8) {
  __shared__ __align__(16) u8 shbuf[8192];
  int bid = blockIdx.x;
  int t = threadIdx.x;
  if (bid >= 8192) {
    int idx = bid - 8192;
    constexpr int TPE = (Hn / 64) * (On / 64);  // 256 tiles/expert
    int z = idx / TPE, rem = idx % TPE;
    int r0 = (rem / (On / 64)) * 64, c0 = (rem % (On / 64)) * 64;
    tcast_f8_64(fc2w + (size_t)z * Hn * On, w2t8 + (size_t)z * Hn * On, Hn, On, r0, c0,
                (uint32_t*)shbuf);
    return;
  }
  constexpr int K = Dn, N = Hn;
  constexpr int NT = K / 64;
  int e = bid >> 10;          // 0..7
  int rb = (bid >> 5) & 31;   // 0..31
  int nb = (bid & 31) * 64;
  int cnt = counts[e];
  if (rb * 64 >= cnt) return;
  int base = 0;
#pragma unroll
  for (int i = 0; i < En; i++) base += (i < e) ? counts[i] : 0;
  u8* As = shbuf;
  u8* Bs = shbuf + 4096;
  int lane = t & 63, w = t >> 6;
  int wr = w >> 1, wc = w & 1;

  int srow = t >> 2;
  int sslot = (t & 3) ^ ((srow >> 1) & 3);
  int scol = sslot * 16;

  int lr = rb * 64 + srow;
  int lrc = lr < cnt ? lr : cnt - 1;
  const u8* aptr = A + (size_t)s2r[base + lrc] * K + scol;
  const u8* bptr = WT + ((size_t)e * N + nb + srow) * K + scol;

  f32x4 zero = {0.f, 0.f, 0.f, 0.f};
  f32x4 acc[2][2];
#pragma unroll
  for (int m = 0; m < 2; m++)
#pragma unroll
    for (int n = 0; n < 2; n++) acc[m][n] = zero;

  int a_r = wr * 32 + (lane & 15);
  int b_r = wc * 32 + (lane & 15);
  int rkey = ((lane & 15) >> 1) & 3;
  int slb = (lane >> 4) >> 1;
  int half = ((lane >> 4) & 1) * 8;

  for (int kt = 0; kt < NT; kt++) {
    gload16(aptr + kt * 64, &As[t * 16]);
    gload16(bptr + kt * 64, &Bs[t * 16]);
    __syncthreads();
#pragma unroll
    for (int kk = 0; kk < 2; kk++) {
      long af[2], bfr[2];
#pragma unroll
      for (int m = 0; m < 2; m++)
        af[m] = *(const long*)(As + (a_r + m * 16) * 64 +
                               (((kk * 2 + slb) ^ rkey) << 4) + half);
#pragma unroll
      for (int n = 0; n < 2; n++)
        bfr[n] = *(const long*)(Bs + (b_r + n * 16) * 64 +
                                (((kk * 2 + slb) ^ rkey) << 4) + half);
#pragma unroll
      for (int m = 0; m < 2; m++)
#pragma unroll
        for (int n = 0; n < 2; n++)
          acc[m][n] = __builtin_amdgcn_mfma_f32_16x16x32_fp8_fp8(af[m], bfr[n], acc[m][n], 0, 0, 0);
    }
    __syncthreads();
  }

  const float INV = 1.0f / WSCALE;
  int lr0 = rb * 64 + wr * 32;
#pragma unroll
  for (int m = 0; m < 2; m++) {
#pragma unroll
    for (int i = 0; i < 4; i++) {
      int orow = lr0 + m * 16 + (lane >> 4) * 4 + i;
      if (orow < cnt) {
        int slot = base + orow;
#pragma unroll
        for (int n = 0; n < 2; n++) {
          int col = nb + wc * 32 + n * 16 + (lane & 15);
          float v = acc[m][n][i] * INV + bias[e * N + col];
          float g = 0.5f * v * (1.0f + erff(v * 0.70710678118654752f));
          outH8[(size_t)slot * N + col] = f2fp8(g);
        }
      }
    }
  }
}

// ---- fc2 fp8 GEMM: 64x64 x 64B-K-step, split-K=2 (r16-r20 proven structure) ----
template <int N, int K, int SPLITK>
__global__ __launch_bounds__(256, 8) void fc2_gemm_kernel(
    const u8* __restrict__ A, const u8* __restrict__ WT,
    const float* __restrict__ bias, const int* __restrict__ counts,
    float* __restrict__ outL, float* __restrict__ outLX) {
  constexpr int NBL = N / 64;
  constexpr int KS = K / SPLITK;
  constexpr int NT = KS / 64;
  int e = blockIdx.z;
  int cnt = counts[e];
  int rb = blockIdx.y;
  if (rb * 64 >= cnt) return;
  int base = 0;
#pragma unroll
  for (int i = 0; i < En; i++) base += (i < e) ? counts[i] : 0;
  int ks = blockIdx.x / NBL;
  int nb = (blockIdx.x % NBL) * 64;
  int k0 = ks * KS;
  __shared__ __align__(16) u8 As[64 * 64];
  __shared__ __align__(16) u8 Bs[64 * 64];
  int t = threadIdx.x;
  int lane = t & 63, w = t >> 6;
  int wr = w >> 1, wc = w & 1;

  int srow = t >> 2;
  int sslot = (t & 3) ^ ((srow >> 1) & 3);
  int scol = sslot * 16;

  int lr = rb * 64 + srow;
  int lrc = lr < cnt ? lr : cnt - 1;
  const u8* aptr = A + (size_t)(base + lrc) * K + k0 + scol;
  const u8* bptr = WT + ((size_t)e * N + nb + srow) * K + k0 + scol;

  f32x4 zero = {0.f, 0.f, 0.f, 0.f};
  f32x4 acc[2][2];
#pragma unroll
  for (int m = 0; m < 2; m++)
#pragma unroll
    for (int n = 0; n < 2; n++) acc[m][n] = zero;

  int a_r = wr * 32 + (lane & 15);
  int b_r = wc * 32 + (lane & 15);
  int rkey = ((lane & 15) >> 1) & 3;
  int slb = (lane >> 4) >> 1;
  int half = ((lane >> 4) & 1) * 8;

  for (int kt = 0; kt < NT; kt++) {
    gload16(aptr + kt * 64, &As[t * 16]);
    gload16(bptr + kt * 64, &Bs[t * 16]);
    __syncthreads();
#pragma unroll
    for (int kk = 0; kk < 2; kk++) {
      long af[2], bfr[2];
#pragma unroll
      for (int m = 0; m < 2; m++)
        af[m] = *(const long*)(As + (a_r + m * 16) * 64 +
                               (((kk * 2 + slb) ^ rkey) << 4) + half);
#pragma unroll
      for (int n = 0; n < 2; n++)
        bfr[n] = *(const long*)(Bs + (b_r + n * 16) * 64 +
                                (((kk * 2 + slb) ^ rkey) << 4) + half);
#pragma unroll
      for (int m = 0; m < 2; m++)
#pragma unroll
        for (int n = 0; n < 2; n++)
          acc[m][n] = __builtin_amdgcn_mfma_f32_16x16x32_fp8_fp8(af[m], bfr[n], acc[m][n], 0, 0, 0);
    }
    __syncthreads();
  }

  const float INV = 1.0f / WSCALE;
  float* dst = (ks > 0) ? outLX : outL;
  int lr0 = rb * 64 + wr * 32;
#pragma unroll
  for (int m = 0; m < 2; m++) {
#pragma unroll
    for (int i = 0; i < 4; i++) {
      int orow = lr0 + m * 16 + (lane >> 4) * 4 + i;
      if (orow < cnt) {
        int slot = base + orow;
#pragma unroll
        for (int n = 0; n < 2; n++) {
          int col = nb + wc * 32 + n * 16 + (lane & 15);
          float v = acc[m][n][i] * INV + (ks == 0 ? bias[e * N + col] : 0.f);
          dst[(size_t)slot * N + col] = v;
        }
      }
    }
  }
}

// ---------------- combine: sum 2 split-K partials, logsoftmax over O=512, weighted sum ----------------
__device__ __forceinline__ float blk_reduce(float v, bool ismax) {
  __shared__ float sbuf[4];
  int lane = threadIdx.x & 63, w = threadIdx.x >> 6;
#pragma unroll
  for (int off = 32; off; off >>= 1) {
    float o = __shfl_down(v, off);
    v = ismax ? fmaxf(v, o) : (v + o);
  }
  __syncthreads();
  if (lane == 0) sbuf[w] = v;
  __syncthreads();
  float r = sbuf[0];
#pragma unroll
  for (int i = 1; i < 4; i++) r = ismax ? fmaxf(r, sbuf[i]) : (r + sbuf[i]);
  return r;
}

__global__ void combine_kernel(const float* __restrict__ l2a, const float* __restrict__ l2x,
                               const int* __restrict__ r2s, const float* __restrict__ gates,
                               float* __restrict__ out) {
  int b = blockIdx.x, t = threadIdx.x;
  float c0 = 0.f, c1 = 0.f;
#pragma unroll
  for (int k = 0; k < 2; k++) {
    int slot = r2s[2 * b + k];
    float g = gates[2 * b + k];
    const float* lp0 = l2a + (size_t)slot * On;
    const float* lp1 = l2x + (size_t)slot * On;
    float v0 = lp0[t] + lp1[t];
    float v1 = lp0[t + 256] + lp1[t + 256];
    float m = blk_reduce(fmaxf(v0, v1), true);
    float s = blk_reduce(expf(v0 - m) + expf(v1 - m), false);
    float lse = m + logf(s);
    c0 += g * expf(v0 - lse);
    c1 += g * expf(v1 - lse);
  }
  const float EPSv = 2.220446049250313e-16f;
  out[(size_t)b * On + t] = logf(fmaxf(c0, EPSv));
  out[(size_t)b * On + t + 256] = logf(fmaxf(c1, EPSv));
}

extern "C" void kernel_launch(void* const* d_in, const int* in_sizes, int n_in,
                              void* d_out, int out_size, void* d_ws, size_t ws_size,
                              hipStream_t stream) {
  const float* x = (const float*)d_in[0];
  const float* wgate = (const float*)d_in[1];
  const float* fc1w = (const float*)d_in[2];
  const float* fc1b = (const float*)d_in[3];
  const float* fc2w = (const float*)d_in[4];
  const float* fc2b = (const float*)d_in[5];
  float* out = (float*)d_out;

  char* ws = (char*)d_ws;
  size_t o = 0;
  u8* x_f8      = (u8*)(ws + o);    o += (size_t)Bn * Dn;              // 2 MB
  u8* w1t8      = (u8*)(ws + o);    o += (size_t)En * Hn * Dn;         // 16 MB [E][H][D] fp8
  u8* w2t8      = (u8*)(ws + o);    o += (size_t)En * On * Hn;         // 8 MB  [E][O][H] fp8
  u8* hbuf8     = (u8*)(ws + o);    o += (size_t)2 * Bn * Hn;          // 4 MB  [slot][H] fp8
  float* l2buf  = (float*)(ws + o); o += (size_t)2 * Bn * On * 4;      // 8 MB partial 0
  float* l2bufX = (float*)(ws + o); o += (size_t)2 * Bn * On * 4;      // 8 MB partial 1
  int* top_idx  = (int*)(ws + o);   o += (size_t)Bn * 2 * 4;
  float* gates  = (float*)(ws + o); o += (size_t)Bn * 2 * 4;
  int* r2s      = (int*)(ws + o);   o += (size_t)Bn * 2 * 4;
  int* s2r      = (int*)(ws + o);   o += (size_t)2 * Bn * 4;
  int* counts   = (int*)(ws + o);   o += 64;
  int* cursors  = (int*)(ws + o);   o += 64;

  hipLaunchKernelGGL(init_kernel, dim3(1), dim3(64), 0, stream, counts, cursors);
  hipLaunchKernelGGL(prep_kernel, dim3(NB_G + NB_T1), dim3(256), 0, stream,
                     x, wgate, fc1w, x_f8, w1t8, top_idx, gates, counts);
  hipLaunchKernelGGL(assign_kernel, dim3(Bn / 256), dim3(256), 0, stream,
                     top_idx, counts, cursors, s2r, r2s);
  // fc1 GEMM (8192 logical blocks, early-exit) + w2 transpose (2048 blocks) fused
  hipLaunchKernelGGL(fc1_fused_kernel, dim3(8192 + 2048), dim3(256), 0, stream,
                     x_f8, w1t8, fc1b, counts, s2r, hbuf8, fc2w, w2t8);
  hipLaunchKernelGGL((fc2_gemm_kernel<On, Hn, 2>), dim3((On / 64) * 2, 32, En), dim3(256),
                     0, stream, hbuf8, w2t8, fc2b, counts, l2buf, l2bufX);
  hipLaunchKernelGGL(combine_kernel, dim3(Bn), dim3(256), 0, stream, l2buf, l2bufX, r2s, gates, out);
}

// Round 26
// 112.046 us; speedup vs baseline: 1.0491x; 1.0293x over previous
//
#include <hip/hip_runtime.h>
#include <stdint.h>

#define Bn 2048
#define Dn 1024
#define Hn 2048
#define On 512
#define En 8

typedef float f32x4 __attribute__((ext_vector_type(4)));
typedef unsigned char u8;

__device__ __forceinline__ void gload16(const void* g, void* l) {
  __builtin_amdgcn_global_load_lds((const uint32_t*)g, (uint32_t*)l, 16, 0, 0);
}

__device__ __forceinline__ u8 f2fp8(float v) {
  int w = __builtin_amdgcn_cvt_pk_fp8_f32(v, v, 0, false);
  return (u8)(w & 0xff);
}

// ---------------- init: zero counts/cursors every launch (determinism) ----------------
__global__ void init_kernel(int* counts, int* cursors) {
  int t = threadIdx.x;
  if (t < En) { counts[t] = 0; cursors[t] = 0; }
}

// == fused prep: gating+x->fp8 (no LDS) | tcast fc1_w->fp8 | tcast fc2_w->fp8 ==
#define NB_G (Bn / 8)                         // 256 blocks x 8 rows
#define NB_T1 ((Dn / 256) * (Hn / 64) * En)   // 4*32*8 = 1024
#define NB_T2 ((Hn / 256) * (On / 64) * En)   // 8*8*8  = 512
#define WSCALE 64.0f

// 256(r) x 64(c) transpose tile -> fp8 (x WSCALE). Stride-65 LDS (2-way banks both sides).
__device__ __forceinline__ void tcast_f8_256(const float* __restrict__ inp,
                                             u8* __restrict__ outp,
                                             int R, int C, int r0, int c0, uint32_t* L) {
  int t = threadIdx.x;
  int cc4 = (t & 15) * 4;   // col base 0..60
  int rg = t >> 4;          // 0..15
#pragma unroll
  for (int p = 0; p < 4; p++) {
    int rbase = p * 64 + rg * 4;
    uint32_t wds[4] = {0, 0, 0, 0};
#pragma unroll
    for (int i = 0; i < 4; i++) {
      float4 v = *(const float4*)&inp[(size_t)(r0 + rbase + i) * C + c0 + cc4];
      wds[0] |= (uint32_t)f2fp8(v.x * WSCALE) << (8 * i);
      wds[1] |= (uint32_t)f2fp8(v.y * WSCALE) << (8 * i);
      wds[2] |= (uint32_t)f2fp8(v.z * WSCALE) << (8 * i);
      wds[3] |= (uint32_t)f2fp8(v.w * WSCALE) << (8 * i);
    }
    int rd = p * 16 + rg;
#pragma unroll
    for (int j = 0; j < 4; j++) L[(cc4 + j) * 65 + rd] = wds[j];
  }
  __syncthreads();
  int c = t >> 2, q = t & 3;  // output row c (0..63), 64B chunk q
  uint32_t dw[16];
#pragma unroll
  for (int i = 0; i < 16; i++) dw[i] = L[c * 65 + q * 16 + i];
  u8* op = &outp[(size_t)(c0 + c) * R + r0 + q * 64];
#pragma unroll
  for (int s = 0; s < 4; s++) {
    int4 o = make_int4((int)dw[4 * s], (int)dw[4 * s + 1], (int)dw[4 * s + 2],
                       (int)dw[4 * s + 3]);
    *(int4*)(op + 16 * s) = o;
  }
}

__global__ __launch_bounds__(256) void prep_kernel(
    const float* __restrict__ x, const float* __restrict__ wg,
    const float* __restrict__ fc1w, const float* __restrict__ fc2w,
    u8* __restrict__ x_f8, u8* __restrict__ w1t8, u8* __restrict__ w2t8,
    int* __restrict__ top_idx, float* __restrict__ gates, int* __restrict__ counts) {
  __shared__ __align__(16) uint32_t smem[64 * 65];  // 16.3 KB transpose tile
  __shared__ int lcnt[En];
  int bid = blockIdx.x;
  int t = threadIdx.x;

  if (bid < NB_G) {
    // ---- gating + x->fp8: 8 rows/block, no LDS (wg read direct, L1-resident) ----
    if (t < En) lcnt[t] = 0;
    __syncthreads();
    int w = t >> 6, lane = t & 63;
#pragma unroll
    for (int r = 0; r < 2; r++) {
      int b = bid * 8 + w * 2 + r;
      const float* xr = x + (size_t)b * Dn;
      u8* xo = x_f8 + (size_t)b * Dn;
      float acc[En];
#pragma unroll
      for (int e = 0; e < En; e++) acc[e] = 0.f;
#pragma unroll
      for (int j = 0; j < 16; j++) {
        int d = lane + j * 64;
        float xv = xr[d];
        xo[d] = f2fp8(xv);
        float4 wa = *(const float4*)(wg + (size_t)d * En);
        float4 wb = *(const float4*)(wg + (size_t)d * En + 4);
        acc[0] += xv * wa.x; acc[1] += xv * wa.y;
        acc[2] += xv * wa.z; acc[3] += xv * wa.w;
        acc[4] += xv * wb.x; acc[5] += xv * wb.y;
        acc[6] += xv * wb.z; acc[7] += xv * wb.w;
      }
#pragma unroll
      for (int off = 32; off; off >>= 1) {
#pragma unroll
        for (int e = 0; e < En; e++) acc[e] += __shfl_down(acc[e], off);
      }
      if (lane == 0) {
        float best = -1e30f, second = -1e30f; int bi = 0, si = 0;
#pragma unroll
        for (int e = 0; e < En; e++) {
          float l = acc[e];
          if (l > best) { second = best; si = bi; best = l; bi = e; }
          else if (l > second) { second = l; si = e; }
        }
        float e1 = expf(second - best);
        float inv = 1.f / (1.f + e1);
        top_idx[2 * b] = bi; top_idx[2 * b + 1] = si;
        gates[2 * b] = inv;  gates[2 * b + 1] = e1 * inv;
        atomicAdd(&lcnt[bi], 1);
        atomicAdd(&lcnt[si], 1);
      }
    }
    __syncthreads();
    if (t < En) {
      int c = lcnt[t];
      if (c) atomicAdd(&counts[t], c);
    }
  } else if (bid < NB_G + NB_T1) {
    int idx = bid - NB_G;
    constexpr int TPE = (Dn / 256) * (Hn / 64);
    int z = idx / TPE, rem = idx % TPE;
    int r0 = (rem / (Hn / 64)) * 256, c0 = (rem % (Hn / 64)) * 64;
    tcast_f8_256(fc1w + (size_t)z * Dn * Hn, w1t8 + (size_t)z * Dn * Hn, Dn, Hn, r0, c0, smem);
  } else {
    int idx = bid - NB_G - NB_T1;
    constexpr int TPE = (Hn / 256) * (On / 64);
    int z = idx / TPE, rem = idx % TPE;
    int r0 = (rem / (On / 64)) * 256, c0 = (rem % (On / 64)) * 64;
    tcast_f8_256(fc2w + (size_t)z * Hn * On, w2t8 + (size_t)z * Hn * On, Hn, On, r0, c0, smem);
  }
}

// -------- assign rows to compact slots (offsets computed inline from counts) --------
__global__ void assign_kernel(const int* __restrict__ top_idx, const int* __restrict__ counts,
                              int* cursors, int* __restrict__ s2r, int* __restrict__ r2s) {
  int b = blockIdx.x * 256 + threadIdx.x;
  if (b >= Bn) return;
  int offs[En];
  int s = 0;
#pragma unroll
  for (int e = 0; e < En; e++) { offs[e] = s; s += counts[e]; }
#pragma unroll
  for (int k = 0; k < 2; k++) {
    int e = top_idx[2 * b + k];
    int pos = atomicAdd(&cursors[e], 1);
    int slot = offs[e] + pos;
    s2r[slot] = b;
    r2s[2 * b + k] = slot;
  }
}

// ---- fp8 grouped GEMM: 64x64 x 64B-K-step, 4 waves (2Mx2N), mfma_f32_16x16x32_fp8_fp8 ----
// r16-r20 proven structure. W pre-scaled x64 -> epilogue unscales 1/64.
template <bool FC1, int N, int K, int SPLITK>
__global__ __launch_bounds__(256, 8) void fp8_gemm_kernel(
    const u8* __restrict__ A, const u8* __restrict__ WT,
    const float* __restrict__ bias, const int* __restrict__ counts,
    const int* __restrict__ s2r,
    u8* __restrict__ outH8, float* __restrict__ outL, float* __restrict__ outL2) {
  constexpr int NBL = N / 64;
  constexpr int KS = K / SPLITK;
  constexpr int NT = KS / 64;
  int e = blockIdx.z;
  int cnt = counts[e];
  int rb = blockIdx.y;
  if (rb * 64 >= cnt) return;
  int base = 0;
#pragma unroll
  for (int i = 0; i < En; i++) base += (i < e) ? counts[i] : 0;
  int ks = blockIdx.x / NBL;
  int nb = (blockIdx.x % NBL) * 64;
  int k0 = ks * KS;
  __shared__ __align__(16) u8 As[64 * 64];  // 4 KB
  __shared__ __align__(16) u8 Bs[64 * 64];  // 4 KB
  int t = threadIdx.x;
  int lane = t & 63, w = t >> 6;
  int wr = w >> 1, wc = w & 1;

  int srow = t >> 2;                           // 0..63 staging row
  int sslot = (t & 3) ^ ((srow >> 1) & 3);     // pre-swizzled global 16B slot
  int scol = sslot * 16;

  int lr = rb * 64 + srow;
  int lrc = lr < cnt ? lr : cnt - 1;
  const u8* aptr = A + (size_t)(FC1 ? s2r[base + lrc] : (base + lrc)) * K + k0 + scol;
  const u8* bptr = WT + ((size_t)e * N + nb + srow) * K + k0 + scol;

  f32x4 zero = {0.f, 0.f, 0.f, 0.f};
  f32x4 acc[2][2];
#pragma unroll
  for (int m = 0; m < 2; m++)
#pragma unroll
    for (int n = 0; n < 2; n++) acc[m][n] = zero;

  int a_r = wr * 32 + (lane & 15);       // A fragment row
  int b_r = wc * 32 + (lane & 15);       // B fragment row
  int rkey = ((lane & 15) >> 1) & 3;     // (row>>1)&3 (row bases mult of 16 -> invariant)
  int slb = (lane >> 4) >> 1;            // logical 16B-slot sub-index (0/1)
  int half = ((lane >> 4) & 1) * 8;      // 8B half within slot

  for (int kt = 0; kt < NT; kt++) {
    gload16(aptr + kt * 64, &As[t * 16]);   // linear dest: row t>>2, slot t&3
    gload16(bptr + kt * 64, &Bs[t * 16]);
    __syncthreads();  // drains vmcnt before LDS reads
#pragma unroll
    for (int kk = 0; kk < 2; kk++) {
      long af[2], bfr[2];
#pragma unroll
      for (int m = 0; m < 2; m++)
        af[m] = *(const long*)(As + (a_r + m * 16) * 64 +
                               (((kk * 2 + slb) ^ rkey) << 4) + half);
#pragma unroll
      for (int n = 0; n < 2; n++)
        bfr[n] = *(const long*)(Bs + (b_r + n * 16) * 64 +
                                (((kk * 2 + slb) ^ rkey) << 4) + half);
#pragma unroll
      for (int m = 0; m < 2; m++)
#pragma unroll
        for (int n = 0; n < 2; n++)
          acc[m][n] = __builtin_amdgcn_mfma_f32_16x16x32_fp8_fp8(af[m], bfr[n], acc[m][n], 0, 0, 0);
    }
    __syncthreads();  // protect LDS before next stage
  }

  // epilogue: D layout col=lane&15, row=(lane>>4)*4+i; unscale 1/64
  const float INV = 1.0f / WSCALE;
  float* dst = (SPLITK > 1 && ks > 0) ? outL2 : outL;
  int lr0 = rb * 64 + wr * 32;
#pragma unroll
  for (int m = 0; m < 2; m++) {
#pragma unroll
    for (int i = 0; i < 4; i++) {
      int orow = lr0 + m * 16 + (lane >> 4) * 4 + i;
      if (orow < cnt) {
        int slot = base + orow;
#pragma unroll
        for (int n = 0; n < 2; n++) {
          int col = nb + wc * 32 + n * 16 + (lane & 15);
          if (FC1) {
            float v = acc[m][n][i] * INV + bias[e * N + col];
            float g = 0.5f * v * (1.0f + erff(v * 0.70710678118654752f));
            outH8[(size_t)slot * N + col] = f2fp8(g);
          } else {
            float v = acc[m][n][i] * INV + (ks == 0 ? bias[e * N + col] : 0.f);
            dst[(size_t)slot * N + col] = v;
          }
        }
      }
    }
  }
}

// ---------------- combine: sum 2 split-K partials, logsoftmax over O=512, weighted sum ----------------
__device__ __forceinline__ float blk_reduce(float v, bool ismax) {
  __shared__ float sbuf[4];
  int lane = threadIdx.x & 63, w = threadIdx.x >> 6;
#pragma unroll
  for (int off = 32; off; off >>= 1) {
    float o = __shfl_down(v, off);
    v = ismax ? fmaxf(v, o) : (v + o);
  }
  __syncthreads();
  if (lane == 0) sbuf[w] = v;
  __syncthreads();
  float r = sbuf[0];
#pragma unroll
  for (int i = 1; i < 4; i++) r = ismax ? fmaxf(r, sbuf[i]) : (r + sbuf[i]);
  return r;
}

__global__ void combine_kernel(const float* __restrict__ l2a, const float* __restrict__ l2b,
                               const int* __restrict__ r2s, const float* __restrict__ gates,
                               float* __restrict__ out) {
  int b = blockIdx.x, t = threadIdx.x;
  float c0 = 0.f, c1 = 0.f;
#pragma unroll
  for (int k = 0; k < 2; k++) {
    int slot = r2s[2 * b + k];
    float g = gates[2 * b + k];
    const float* lp0 = l2a + (size_t)slot * On;
    const float* lp1 = l2b + (size_t)slot * On;
    float v0 = lp0[t] + lp1[t];
    float v1 = lp0[t + 256] + lp1[t + 256];
    float m = blk_reduce(fmaxf(v0, v1), true);
    float s = blk_reduce(expf(v0 - m) + expf(v1 - m), false);
    float lse = m + logf(s);
    c0 += g * expf(v0 - lse);
    c1 += g * expf(v1 - lse);
  }
  const float EPSv = 2.220446049250313e-16f;
  out[(size_t)b * On + t] = logf(fmaxf(c0, EPSv));
  out[(size_t)b * On + t + 256] = logf(fmaxf(c1, EPSv));
}

extern "C" void kernel_launch(void* const* d_in, const int* in_sizes, int n_in,
                              void* d_out, int out_size, void* d_ws, size_t ws_size,
                              hipStream_t stream) {
  const float* x = (const float*)d_in[0];
  const float* wgate = (const float*)d_in[1];
  const float* fc1w = (const float*)d_in[2];
  const float* fc1b = (const float*)d_in[3];
  const float* fc2w = (const float*)d_in[4];
  const float* fc2b = (const float*)d_in[5];
  float* out = (float*)d_out;

  char* ws = (char*)d_ws;
  size_t o = 0;
  u8* x_f8     = (u8*)(ws + o);    o += (size_t)Bn * Dn;          // 2 MB
  u8* w1t8     = (u8*)(ws + o);    o += (size_t)En * Hn * Dn;     // 16 MB [E][H][D] fp8
  u8* w2t8     = (u8*)(ws + o);    o += (size_t)En * On * Hn;     // 8 MB  [E][O][H] fp8
  u8* hbuf8    = (u8*)(ws + o);    o += (size_t)2 * Bn * Hn;      // 4 MB  [slot][H] fp8
  float* l2buf = (float*)(ws + o); o += (size_t)2 * Bn * On * 4;  // 8 MB partial 0
  int* top_idx = (int*)(ws + o);   o += (size_t)Bn * 2 * 4;
  float* gates = (float*)(ws + o); o += (size_t)Bn * 2 * 4;
  int* r2s     = (int*)(ws + o);   o += (size_t)Bn * 2 * 4;
  int* s2r     = (int*)(ws + o);   o += (size_t)2 * Bn * 4;
  int* counts  = (int*)(ws + o);   o += 64;
  int* cursors = (int*)(ws + o);   o += 64;
  // split-K partial 1 (8 MB) aliases w1t8 (16 MB): w1t8 is fully consumed by fc1
  // (completes before fc2 starts, same stream) and rewritten by prep each launch.
  float* l2buf1 = (float*)w1t8;

  hipLaunchKernelGGL(init_kernel, dim3(1), dim3(64), 0, stream, counts, cursors);
  hipLaunchKernelGGL(prep_kernel, dim3(NB_G + NB_T1 + NB_T2), dim3(256), 0, stream,
                     x, wgate, fc1w, fc2w, x_f8, w1t8, w2t8, top_idx, gates, counts);
  hipLaunchKernelGGL(assign_kernel, dim3(Bn / 256), dim3(256), 0, stream,
                     top_idx, counts, cursors, s2r, r2s);
  hipLaunchKernelGGL((fp8_gemm_kernel<true, Hn, Dn, 1>), dim3(Hn / 64, 32, En), dim3(256),
                     0, stream, x_f8, w1t8, fc1b, counts, s2r, hbuf8,
                     (float*)nullptr, (float*)nullptr);
  hipLaunchKernelGGL((fp8_gemm_kernel<false, On, Hn, 2>), dim3((On / 64) * 2, 32, En), dim3(256),
                     0, stream, hbuf8, w2t8, fc2b, counts, s2r, (u8*)nullptr,
                     l2buf, l2buf1);
  hipLaunchKernelGGL(combine_kernel, dim3(Bn), dim3(256), 0, stream, l2buf, l2buf1, r2s, gates, out);
}